// Round 5
// baseline (1694.457 us; speedup 1.0000x reference)
//
#include <hip/hip_runtime.h>

#define NEMB 1024
#define CDIM 256
#define NPOS 131072            // 32*64*64 positions
#define Z_ELEMS 33554432       // 32*256*64*64

// d_out is FLOAT32, flat layout [z_q | cl | cml | indices] (verified r0/r5).
#define SC_OFF  ((size_t)33554432)
#define IDX_OFF ((size_t)33554434)

#define CAP 320                 // candidate list cap per wave (E~115, >10 sigma)
#define EPS 3.0e-3f             // >= certified |key - (d_ref - A)| bound (~1.5e-3)
#define NEG2S (-1.953125e-3f)   // -2/1024 = -2^-9, exact pow2

typedef _Float16 half8 __attribute__((ext_vector_type(8)));
typedef float f32x4 __attribute__((ext_vector_type(4)));

// Bitwise replication of numpy pairwise_sum of a[i]^2 over 256 floats with a
// stride: n=256 -> split 128+128; each 128-block uses 8 stride-8 accumulators
// combined ((r0+r1)+(r2+r3))+((r4+r5)+(r6+r7)). FP contraction OFF.
__device__ __forceinline__ float np_pairwise_sq256_s(const float* a, int stride) {
#pragma clang fp contract(off)
  float s0, s1;
  {
    float r[8];
#pragma unroll
    for (int j = 0; j < 8; ++j) { float v = a[j * stride]; r[j] = v * v; }
#pragma unroll
    for (int i = 8; i < 128; i += 8) {
#pragma unroll
      for (int j = 0; j < 8; ++j) { float v = a[(i + j) * stride]; r[j] += v * v; }
    }
    s0 = ((r[0] + r[1]) + (r[2] + r[3])) + ((r[4] + r[5]) + (r[6] + r[7]));
  }
  {
    float r[8];
#pragma unroll
    for (int j = 0; j < 8; ++j) { float v = a[(128 + j) * stride]; r[j] = v * v; }
#pragma unroll
    for (int i = 8; i < 128; i += 8) {
#pragma unroll
      for (int j = 0; j < 8; ++j) { float v = a[(128 + i + j) * stride]; r[j] += v * v; }
    }
    s1 = ((r[0] + r[1]) + (r[2] + r[3])) + ((r[4] + r[5]) + (r[6] + r[7]));
  }
  return s0 + s1;
}

// Prep (REVERTED to the r3 known-good version: the r4 16-lane shuffle tree
// executed __shfl_xor under a divergent lane==0 branch -> corrupted Bsq ->
// wrong argmins). Bsq: serial lane-0 exact np pairwise. Codebook -> fp16
// scaled by 2^10 (exact pow2 scale in fp32, then RNE fp16; no subnormals).
__global__ void vq_prep(const float* __restrict__ cb, float* __restrict__ Bsq,
                        _Float16* __restrict__ cb16, double* __restrict__ loss_acc) {
  const int k = blockIdx.x, lane = threadIdx.x;
  if (k == 0 && lane == 0) *loss_acc = 0.0;
  if (lane == 0) Bsq[k] = np_pairwise_sq256_s(cb + (size_t)k * CDIM, 1);
  const float* row = cb + (size_t)k * CDIM;
#pragma unroll
  for (int i = 0; i < 4; ++i) {
    int c = (lane << 2) + i;
    cb16[((size_t)k << 8) + c] = (_Float16)(row[c] * 1024.0f);
  }
}

#define LOADB(buf, t) do {                                                     \
    const _Float16* bp_ = cb16 + ((((t) << 4) + col) << 8) + (krow << 3);      \
    _Pragma("unroll")                                                          \
    for (int ks_ = 0; ks_ < 8; ++ks_) (buf)[ks_] = *(const half8*)(bp_ + (ks_ << 5)); \
  } while (0)

#define TILE_CORE(buf)                                                         \
  f32x4 ac0 = {0.f, 0.f, 0.f, 0.f}, ac1 = ac0, ac2 = ac0, ac3 = ac0;           \
  _Pragma("unroll")                                                            \
  for (int ks_ = 0; ks_ < 8; ++ks_) {                                          \
    ac0 = __builtin_amdgcn_mfma_f32_16x16x32_f16(a[0][ks_], (buf)[ks_], ac0, 0, 0, 0); \
    ac1 = __builtin_amdgcn_mfma_f32_16x16x32_f16(a[1][ks_], (buf)[ks_], ac1, 0, 0, 0); \
    ac2 = __builtin_amdgcn_mfma_f32_16x16x32_f16(a[2][ks_], (buf)[ks_], ac2, 0, 0, 0); \
    ac3 = __builtin_amdgcn_mfma_f32_16x16x32_f16(a[3][ks_], (buf)[ks_], ac3, 0, 0, 0); \
  }

#define TILE1(buf, t) do {                                                     \
    const float Bk = Bs[((t) << 4) + col];                                     \
    TILE_CORE(buf)                                                             \
    _Pragma("unroll") for (int r_ = 0; r_ < 4; ++r_) {                         \
      mv[0][r_] = fminf(mv[0][r_], __builtin_fmaf(NEG2S, ac0[r_], Bk));        \
      mv[1][r_] = fminf(mv[1][r_], __builtin_fmaf(NEG2S, ac1[r_], Bk));        \
      mv[2][r_] = fminf(mv[2][r_], __builtin_fmaf(NEG2S, ac2[r_], Bk));        \
      mv[3][r_] = fminf(mv[3][r_], __builtin_fmaf(NEG2S, ac3[r_], Bk));        \
    }                                                                          \
  } while (0)

#define P2ONE(accv, m, t)                                                      \
  _Pragma("unroll") for (int r_ = 0; r_ < 4; ++r_) {                           \
    float key_ = __builtin_fmaf(NEG2S, (accv)[r_], Bk);                        \
    if (key_ <= mv[m][r_]) {                                                   \
      int s_ = atomicAdd(&candn[wv], 1);                                       \
      if (s_ < CAP) { candp[wv][s_] = (m << 4) + (krow << 2) + r_;             \
                      candk[wv][s_] = ((t) << 4) + col; }                      \
    }                                                                          \
  }

#define TILE2(buf, t) do {                                                     \
    const float Bk = Bs[((t) << 4) + col];                                     \
    TILE_CORE(buf)                                                             \
    P2ONE(ac0, 0, t) P2ONE(ac1, 1, t) P2ONE(ac2, 2, t) P2ONE(ac3, 3, t)        \
  } while (0)

// 8 waves/block (one bh each), 256 blocks -> 16 waves/CU = 4 waves/SIMD
// (VGPR 128 x 4 = 512 exactly fills the file). Per-wave algorithm is
// bit-identical to the verified r3 kernel: Phase 1 fp16-MFMA approx keys +
// per-position min; Phase 2 recompute (bitwise-same keys) collecting
// candidates key <= min+EPS; exact fp32 np-chain re-eval picks the
// bitwise-correct argmin (first-index ties).
__global__ __launch_bounds__(512, 4)
void vq_main(const float* __restrict__ z, const float* __restrict__ cb,
             const _Float16* __restrict__ cb16, const float* __restrict__ Bsq,
             float* __restrict__ out, double* __restrict__ loss_acc) {
  __shared__ float A_lds[8][64];
  __shared__ float Bs[NEMB];
  __shared__ int   candp[8][CAP];
  __shared__ int   candk[8][CAP];
  __shared__ float candd[8][CAP];
  __shared__ int   candn[8];

  const int tid = threadIdx.x;
  const int wv = tid >> 6, lane = tid & 63;
  const int bh = (blockIdx.x << 3) | wv;
  const int zoff = ((bh >> 6) << 20) | ((bh & 63) << 6);   // b*CDIM*4096 + h*64
  const int col = lane & 15;     // A-row / B-col / D-col sub-index
  const int krow = lane >> 4;    // k-group 0..3

  for (int i = tid; i < NEMB; i += 512) Bs[i] = Bsq[i];
  A_lds[wv][lane] = np_pairwise_sq256_s(z + zoff + lane, 4096);  // ||z||^2, np order
  if (lane == 0) candn[wv] = 0;
  __syncthreads();

  // a_frags resident: a[m][ks] elem j = fp16(z[c = ks*32+krow*8+j][w = m*16+col])
  half8 a[4][8];
#pragma unroll
  for (int m = 0; m < 4; ++m)
#pragma unroll
    for (int ks = 0; ks < 8; ++ks)
#pragma unroll
      for (int j = 0; j < 8; ++j) {
        float v = z[zoff + ((ks * 32 + krow * 8 + j) << 12) + (m * 16 + col)];
        a[m][ks][j] = (_Float16)v;
      }

  // ---- Phase 1: min key per position ----
  float mv[4][4];
#pragma unroll
  for (int m = 0; m < 4; ++m)
#pragma unroll
    for (int r = 0; r < 4; ++r) mv[m][r] = INFINITY;

  half8 b0[8], b1[8];
  LOADB(b0, 0);
  for (int t = 0; t < 64; t += 2) {
    LOADB(b1, t + 1);
    TILE1(b0, t);
    if (t + 2 < 64) LOADB(b0, t + 2);
    TILE1(b1, t + 1);
  }

  // Reduce min across the 16 lanes (same krow group) holding different codes
  // for the same positions; then thr = min + EPS, kept in-register.
#pragma unroll
  for (int m = 0; m < 4; ++m)
#pragma unroll
    for (int r = 0; r < 4; ++r) {
      float v = mv[m][r];
      v = fminf(v, __shfl_xor(v, 1));
      v = fminf(v, __shfl_xor(v, 2));
      v = fminf(v, __shfl_xor(v, 4));
      v = fminf(v, __shfl_xor(v, 8));
      mv[m][r] = v + EPS;
    }

  // ---- Phase 2: recompute (bitwise-same) keys, collect candidates ----
  LOADB(b0, 0);
  for (int t = 0; t < 64; t += 2) {
    LOADB(b1, t + 1);
    TILE2(b0, t);
    if (t + 2 < 64) LOADB(b0, t + 2);
    TILE2(b1, t + 1);
  }

  // ---- Exact np-chain evaluation of candidates (lane-parallel) ----
  int n = candn[wv];
  if (n > CAP) n = CAP;
  for (int base = 0; base < n; base += 64) {
    int i = base + lane;
    if (i < n) {
      const int w = candp[wv][i], k = candk[wv][i];
      const float* zp = z + zoff + w;
      const float* ep = cb + ((size_t)k << 8);
      float acc = 0.0f;                     // BLAS chain: sequential ascending c
#pragma unroll 8
      for (int c = 0; c < CDIM; ++c)
        acc = __builtin_fmaf(zp[(size_t)c << 12], ep[c], acc);
      float tt = A_lds[wv][w] + Bs[k];      // fl(A+B)
      candd[wv][i] = __builtin_fmaf(-2.0f, acc, tt);  // fl(t - 2C), single rounding
    }
  }

  // Final per-position selection: lexicographic (d, k) = np first-index ties.
  float bd = INFINITY; int bk = 0;
  for (int i = 0; i < n; ++i) {
    if (candp[wv][i] == lane) {
      float d = candd[wv][i]; int k = candk[wv][i];
      if (d < bd || (d == bd && k < bk)) { bd = d; bk = k; }
    }
  }
  out[IDX_OFF + (size_t)bh * 64 + lane] = (float)bk;   // fp32 index

  // ---- Epilogue: z_q = fl(z + fl(e - z)); loss = sum (e-z)^2 in double ----
  double lsum = 0.0;
  const float* erow = cb + ((size_t)bk << 8);
  for (int c = 0; c < CDIM; ++c) {
    const float zz = z[zoff + (c << 12) + lane];
    const float diff = erow[c] - zz;
    lsum += (double)diff * (double)diff;
    out[zoff + (c << 12) + lane] = zz + diff;
  }
  for (int off = 32; off; off >>= 1) lsum += __shfl_down(lsum, off);
  if (lane == 0) atomicAdd(loss_acc, lsum);
}

__global__ void vq_finalize(const double* __restrict__ loss_acc,
                            float* __restrict__ out) {
  double m = *loss_acc / (double)Z_ELEMS;
  out[SC_OFF] = (float)m;
  out[SC_OFF + 1] = (float)(0.25 * m);
}

extern "C" void kernel_launch(void* const* d_in, const int* in_sizes, int n_in,
                              void* d_out, int out_size, void* d_ws,
                              size_t ws_size, hipStream_t stream) {
  (void)n_in; (void)ws_size; (void)out_size;
  const float* z;
  const float* cb;
  if (in_sizes[0] == Z_ELEMS) {
    z = (const float*)d_in[0];
    cb = (const float*)d_in[1];
  } else {
    z = (const float*)d_in[1];
    cb = (const float*)d_in[0];
  }
  float* out = (float*)d_out;
  double* loss = (double*)d_ws;                       // 8 B
  float* Bsq = (float*)((char*)d_ws + 256);           // 4 KB
  _Float16* cb16 = (_Float16*)((char*)d_ws + 8192);   // 512 KB (ws >= 520.2 KB)

  vq_prep<<<dim3(NEMB), dim3(64), 0, stream>>>(cb, Bsq, cb16, loss);
  vq_main<<<dim3(256), dim3(512), 0, stream>>>(z, cb, cb16, Bsq, out, loss);
  vq_finalize<<<dim3(1), dim3(1), 0, stream>>>(loss, out);
}

// Round 6
// 627.875 us; speedup vs baseline: 2.6987x; 2.6987x over previous
//
#include <hip/hip_runtime.h>

#define NEMB 1024
#define CDIM 256
#define Z_ELEMS 33554432       // 32*256*64*64

// d_out is FLOAT32, flat layout [z_q | cl | cml | indices] (verified r0/r5).
#define SC_OFF  ((size_t)33554432)
#define IDX_OFF ((size_t)33554434)

#define CAPW 192                // cand cap per wave (32 pos, E~58, >15 sigma)
#define EPS 3.0e-3f             // >= certified |key - (d_ref - A)| bound (~1.5e-3)
#define NEG2S (-1.953125e-3f)   // -2/1024 = -2^-9, exact pow2

typedef _Float16 half8 __attribute__((ext_vector_type(8)));
typedef float f32x4 __attribute__((ext_vector_type(4)));

// Bitwise replication of numpy pairwise_sum of a[i]^2 over 256 floats with a
// stride: n=256 -> split 128+128; each 128-block uses 8 stride-8 accumulators
// combined ((r0+r1)+(r2+r3))+((r4+r5)+(r6+r7)). FP contraction OFF.
__device__ __forceinline__ float np_pairwise_sq256_s(const float* a, int stride) {
#pragma clang fp contract(off)
  float s0, s1;
  {
    float r[8];
#pragma unroll
    for (int j = 0; j < 8; ++j) { float v = a[j * stride]; r[j] = v * v; }
#pragma unroll
    for (int i = 8; i < 128; i += 8) {
#pragma unroll
      for (int j = 0; j < 8; ++j) { float v = a[(i + j) * stride]; r[j] += v * v; }
    }
    s0 = ((r[0] + r[1]) + (r[2] + r[3])) + ((r[4] + r[5]) + (r[6] + r[7]));
  }
  {
    float r[8];
#pragma unroll
    for (int j = 0; j < 8; ++j) { float v = a[(128 + j) * stride]; r[j] = v * v; }
#pragma unroll
    for (int i = 8; i < 128; i += 8) {
#pragma unroll
      for (int j = 0; j < 8; ++j) { float v = a[(128 + i + j) * stride]; r[j] += v * v; }
    }
    s1 = ((r[0] + r[1]) + (r[2] + r[3])) + ((r[4] + r[5]) + (r[6] + r[7]));
  }
  return s0 + s1;
}

// Prep (r3 known-good; do NOT re-parallelize Bsq — r4's divergent-shuffle bug).
__global__ void vq_prep(const float* __restrict__ cb, float* __restrict__ Bsq,
                        _Float16* __restrict__ cb16, double* __restrict__ loss_acc) {
  const int k = blockIdx.x, lane = threadIdx.x;
  if (k == 0 && lane == 0) *loss_acc = 0.0;
  if (lane == 0) Bsq[k] = np_pairwise_sq256_s(cb + (size_t)k * CDIM, 1);
  const float* row = cb + (size_t)k * CDIM;
#pragma unroll
  for (int i = 0; i < 4; ++i) {
    int c = (lane << 2) + i;
    cb16[((size_t)k << 8) + c] = (_Float16)(row[c] * 1024.0f);
  }
}

// 512 thr = 8 waves = 4 bh x 2 waves (mhalf 0/1 -> 32 positions each).
// B tiles (16 codes x 256 fp16) staged in LDS per block, double-buffered,
// shared by all 8 waves (kills the 8x-redundant per-wave L1 B-stream that
// r3 counters showed as the TA bottleneck). Row pad +16B (528B stride)
// makes frag ds_read_b128 bank-uniform. a-frags halve to 64 VGPR ->
// amdgpu_waves_per_eu(4) targets VGPR<=128 -> 4 waves/EU.
// All key numerics bit-identical to verified r3.
__global__ __launch_bounds__(512) __attribute__((amdgpu_waves_per_eu(4)))
void vq_main(const float* __restrict__ z, const float* __restrict__ cb,
             const _Float16* __restrict__ cb16, const float* __restrict__ Bsq,
             float* __restrict__ out, double* __restrict__ loss_acc) {
  __shared__ __align__(16) _Float16 Bt[2][16 * 264];  // 264-half rows (pad 8)
  __shared__ float Bs[NEMB];
  __shared__ float A_lds[4][64];
  __shared__ int   candp[8][CAPW];
  __shared__ int   candk[8][CAPW];
  __shared__ float candd[8][CAPW];
  __shared__ int   candn[8];
  __shared__ double wsum[8];

  const int tid = threadIdx.x;
  const int wv = tid >> 6, lane = tid & 63;
  const int bhl = wv >> 1, mhalf = wv & 1;
  const int bh = (blockIdx.x << 2) | bhl;
  const int zoff = ((bh >> 6) << 20) | ((bh & 63) << 6);  // b*CDIM*4096 + h*64
  const int col = lane & 15, krow = lane >> 4;
  const int srow = tid >> 5, schunk = tid & 31;  // staging: 16 rows x 32 x 16B

  for (int i = tid; i < NEMB; i += 512) Bs[i] = Bsq[i];
  if (lane < 32)
    A_lds[bhl][(mhalf << 5) + lane] =
        np_pairwise_sq256_s(z + zoff + (mhalf << 5) + lane, 4096);  // np order
  if (lane == 0) candn[wv] = 0;

  // a-frags: wave's 32 positions (m_global in {2*mhalf, 2*mhalf+1})
  half8 a[2][8];
#pragma unroll
  for (int m = 0; m < 2; ++m) {
    const int wbase = (((mhalf << 1) + m) << 4) + col;
#pragma unroll
    for (int ks = 0; ks < 8; ++ks)
#pragma unroll
      for (int j = 0; j < 8; ++j)
        a[m][ks][j] = (_Float16)z[zoff + ((ks * 32 + krow * 8 + j) << 12) + wbase];
  }

  float mv[2][4];
#pragma unroll
  for (int m = 0; m < 2; ++m)
#pragma unroll
    for (int r = 0; r < 4; ++r) mv[m][r] = INFINITY;

  // ===== pass 1: min key per position =====
  {
    half8 v0 = *(const half8*)(cb16 + (srow << 8) + (schunk << 3));
    *(half8*)&Bt[0][srow * 264 + (schunk << 3)] = v0;
  }
  __syncthreads();
  for (int t = 0; t < 64; ++t) {
    const int cur = t & 1;
    const bool hn = (t + 1) < 64;
    half8 nv;
    if (hn) nv = *(const half8*)(cb16 + ((((t + 1) << 4) | srow) << 8) + (schunk << 3));
    const _Float16* bp = &Bt[cur][col * 264 + (krow << 3)];
    f32x4 ac0 = {0.f, 0.f, 0.f, 0.f}, ac1 = ac0;
#pragma unroll
    for (int ks = 0; ks < 8; ++ks) {
      const half8 b = *(const half8*)(bp + ks * 32);
      ac0 = __builtin_amdgcn_mfma_f32_16x16x32_f16(a[0][ks], b, ac0, 0, 0, 0);
      ac1 = __builtin_amdgcn_mfma_f32_16x16x32_f16(a[1][ks], b, ac1, 0, 0, 0);
    }
    const float Bk = Bs[(t << 4) + col];
#pragma unroll
    for (int r = 0; r < 4; ++r) {
      mv[0][r] = fminf(mv[0][r], __builtin_fmaf(NEG2S, ac0[r], Bk));
      mv[1][r] = fminf(mv[1][r], __builtin_fmaf(NEG2S, ac1[r], Bk));
    }
    if (hn) *(half8*)&Bt[cur ^ 1][srow * 264 + (schunk << 3)] = nv;
    __syncthreads();
  }

  // min over the 16 cols of each krow group (all 64 lanes active); +EPS
#pragma unroll
  for (int m = 0; m < 2; ++m)
#pragma unroll
    for (int r = 0; r < 4; ++r) {
      float v = mv[m][r];
      v = fminf(v, __shfl_xor(v, 1));
      v = fminf(v, __shfl_xor(v, 2));
      v = fminf(v, __shfl_xor(v, 4));
      v = fminf(v, __shfl_xor(v, 8));
      mv[m][r] = v + EPS;
    }

  // ===== pass 2: recompute (bitwise-same) keys, collect candidates =====
  {
    half8 v0 = *(const half8*)(cb16 + (srow << 8) + (schunk << 3));
    *(half8*)&Bt[0][srow * 264 + (schunk << 3)] = v0;
  }
  __syncthreads();
  for (int t = 0; t < 64; ++t) {
    const int cur = t & 1;
    const bool hn = (t + 1) < 64;
    half8 nv;
    if (hn) nv = *(const half8*)(cb16 + ((((t + 1) << 4) | srow) << 8) + (schunk << 3));
    const _Float16* bp = &Bt[cur][col * 264 + (krow << 3)];
    f32x4 ac0 = {0.f, 0.f, 0.f, 0.f}, ac1 = ac0;
#pragma unroll
    for (int ks = 0; ks < 8; ++ks) {
      const half8 b = *(const half8*)(bp + ks * 32);
      ac0 = __builtin_amdgcn_mfma_f32_16x16x32_f16(a[0][ks], b, ac0, 0, 0, 0);
      ac1 = __builtin_amdgcn_mfma_f32_16x16x32_f16(a[1][ks], b, ac1, 0, 0, 0);
    }
    const float Bk = Bs[(t << 4) + col];
#pragma unroll
    for (int r = 0; r < 4; ++r) {
      const float k0 = __builtin_fmaf(NEG2S, ac0[r], Bk);
      if (k0 <= mv[0][r]) {
        const int s = atomicAdd(&candn[wv], 1);
        if (s < CAPW) { candp[wv][s] = (krow << 2) + r; candk[wv][s] = (t << 4) + col; }
      }
      const float k1 = __builtin_fmaf(NEG2S, ac1[r], Bk);
      if (k1 <= mv[1][r]) {
        const int s = atomicAdd(&candn[wv], 1);
        if (s < CAPW) { candp[wv][s] = 16 + (krow << 2) + r; candk[wv][s] = (t << 4) + col; }
      }
    }
    if (hn) *(half8*)&Bt[cur ^ 1][srow * 264 + (schunk << 3)] = nv;
    __syncthreads();
  }

  // ===== exact np-chain re-eval (float4 ep loads; same sequential chain) ====
  int n = candn[wv];
  if (n > CAPW) n = CAPW;
  for (int base = 0; base < n; base += 64) {
    const int i = base + lane;
    if (i < n) {
      const int wl = candp[wv][i], k = candk[wv][i];
      const int wg = (mhalf << 5) + wl;
      const float* zp = z + zoff + wg;
      const float* ep = cb + ((size_t)k << 8);
      float acc = 0.0f;                    // BLAS chain: sequential ascending c
#pragma unroll 16
      for (int c = 0; c < CDIM; c += 4) {
        const float4 ef = *(const float4*)(ep + c);
        acc = __builtin_fmaf(zp[(c + 0) << 12], ef.x, acc);
        acc = __builtin_fmaf(zp[(c + 1) << 12], ef.y, acc);
        acc = __builtin_fmaf(zp[(c + 2) << 12], ef.z, acc);
        acc = __builtin_fmaf(zp[(c + 3) << 12], ef.w, acc);
      }
      const float tt = A_lds[bhl][wg] + Bs[k];        // fl(A+B)
      candd[wv][i] = __builtin_fmaf(-2.0f, acc, tt);  // fl(t - 2C)
    }
  }
  __syncthreads();

  // selection: lanes 0..31 own local positions; lexicographic (d,k) = np ties
  float bd = INFINITY; int bk = 0;
  for (int i = 0; i < n; ++i) {
    if (candp[wv][i] == lane) {
      const float d = candd[wv][i]; const int k = candk[wv][i];
      if (d < bd || (d == bd && k < bk)) { bd = d; bk = k; }
    }
  }
  if (lane < 32)
    out[IDX_OFF + (size_t)bh * 64 + (mhalf << 5) + lane] = (float)bk;
  const int bkp = __shfl(bk, lane & 31);   // all lanes: idx of position lane&31

  // ===== epilogue: z_q = fl(z + fl(e - z)); loss in double =====
  const int p = lane & 31, chalf = lane >> 5;
  const int wg = (mhalf << 5) + p;
  const float* erow = cb + ((size_t)bkp << 8) + (chalf << 7);
  double lsum = 0.0;
  for (int c4 = 0; c4 < 32; ++c4) {
    const float4 ef = *(const float4*)(erow + (c4 << 2));
    const int c = (chalf << 7) + (c4 << 2);
    { const float zz = z[zoff + ((c + 0) << 12) + wg]; const float df = ef.x - zz;
      lsum += (double)df * (double)df; out[zoff + ((c + 0) << 12) + wg] = zz + df; }
    { const float zz = z[zoff + ((c + 1) << 12) + wg]; const float df = ef.y - zz;
      lsum += (double)df * (double)df; out[zoff + ((c + 1) << 12) + wg] = zz + df; }
    { const float zz = z[zoff + ((c + 2) << 12) + wg]; const float df = ef.z - zz;
      lsum += (double)df * (double)df; out[zoff + ((c + 2) << 12) + wg] = zz + df; }
    { const float zz = z[zoff + ((c + 3) << 12) + wg]; const float df = ef.w - zz;
      lsum += (double)df * (double)df; out[zoff + ((c + 3) << 12) + wg] = zz + df; }
  }
  for (int off = 32; off; off >>= 1) lsum += __shfl_down(lsum, off);
  if (lane == 0) wsum[wv] = lsum;
  __syncthreads();
  if (tid == 0) {
    double tt = 0.0;
#pragma unroll
    for (int v = 0; v < 8; ++v) tt += wsum[v];
    atomicAdd(loss_acc, tt);
  }
}

__global__ void vq_finalize(const double* __restrict__ loss_acc,
                            float* __restrict__ out) {
  double m = *loss_acc / (double)Z_ELEMS;
  out[SC_OFF] = (float)m;
  out[SC_OFF + 1] = (float)(0.25 * m);
}

extern "C" void kernel_launch(void* const* d_in, const int* in_sizes, int n_in,
                              void* d_out, int out_size, void* d_ws,
                              size_t ws_size, hipStream_t stream) {
  (void)n_in; (void)ws_size; (void)out_size;
  const float* z;
  const float* cb;
  if (in_sizes[0] == Z_ELEMS) {
    z = (const float*)d_in[0];
    cb = (const float*)d_in[1];
  } else {
    z = (const float*)d_in[1];
    cb = (const float*)d_in[0];
  }
  float* out = (float*)d_out;
  double* loss = (double*)d_ws;                       // 8 B
  float* Bsq = (float*)((char*)d_ws + 256);           // 4 KB
  _Float16* cb16 = (_Float16*)((char*)d_ws + 8192);   // 512 KB (ws >= 520.2 KB)

  vq_prep<<<dim3(NEMB), dim3(64), 0, stream>>>(cb, Bsq, cb16, loss);
  vq_main<<<dim3(512), dim3(512), 0, stream>>>(z, cb, cb16, Bsq, out, loss);
  vq_finalize<<<dim3(1), dim3(1), 0, stream>>>(loss, out);
}

// Round 7
// 569.640 us; speedup vs baseline: 2.9746x; 1.1022x over previous
//
#include <hip/hip_runtime.h>

#define NEMB 1024
#define CDIM 256
#define Z_ELEMS 33554432       // 32*256*64*64

// d_out is FLOAT32, flat layout [z_q | cl | cml | indices] (verified r0/r5).
#define SC_OFF  ((size_t)33554432)
#define IDX_OFF ((size_t)33554434)

#define CAPB 512                // block candidate cap (64 pos, E~115, >30 sigma)
#define EPS 3.0e-3f             // >= certified |key - (d_ref - A)| bound (~1.5e-3)
#define NEG2S (-1.953125e-3f)   // -2/1024 = -2^-9, exact pow2

typedef _Float16 half8 __attribute__((ext_vector_type(8)));
typedef float f32x4 __attribute__((ext_vector_type(4)));

// Bitwise replication of numpy pairwise_sum of a[i]^2 over 256 floats with a
// stride: n=256 -> split 128+128; each 128-block uses 8 stride-8 accumulators
// combined ((r0+r1)+(r2+r3))+((r4+r5)+(r6+r7)). FP contraction OFF.
__device__ __forceinline__ float np_pairwise_sq256_s(const float* a, int stride) {
#pragma clang fp contract(off)
  float s0, s1;
  {
    float r[8];
#pragma unroll
    for (int j = 0; j < 8; ++j) { float v = a[j * stride]; r[j] = v * v; }
#pragma unroll
    for (int i = 8; i < 128; i += 8) {
#pragma unroll
      for (int j = 0; j < 8; ++j) { float v = a[(i + j) * stride]; r[j] += v * v; }
    }
    s0 = ((r[0] + r[1]) + (r[2] + r[3])) + ((r[4] + r[5]) + (r[6] + r[7]));
  }
  {
    float r[8];
#pragma unroll
    for (int j = 0; j < 8; ++j) { float v = a[(128 + j) * stride]; r[j] = v * v; }
#pragma unroll
    for (int i = 8; i < 128; i += 8) {
#pragma unroll
      for (int j = 0; j < 8; ++j) { float v = a[(128 + i + j) * stride]; r[j] += v * v; }
    }
    s1 = ((r[0] + r[1]) + (r[2] + r[3])) + ((r[4] + r[5]) + (r[6] + r[7]));
  }
  return s0 + s1;
}

// Prep (r3 known-good; do NOT re-parallelize Bsq — r4's divergent-shuffle bug).
__global__ void vq_prep(const float* __restrict__ cb, float* __restrict__ Bsq,
                        _Float16* __restrict__ cb16, double* __restrict__ loss_acc) {
  const int k = blockIdx.x, lane = threadIdx.x;
  if (k == 0 && lane == 0) *loss_acc = 0.0;
  if (lane == 0) Bsq[k] = np_pairwise_sq256_s(cb + (size_t)k * CDIM, 1);
  const float* row = cb + (size_t)k * CDIM;
#pragma unroll
  for (int i = 0; i < 4; ++i) {
    int c = (lane << 2) + i;
    cb16[((size_t)k << 8) + c] = (_Float16)(row[c] * 1024.0f);
  }
}

#define LOADB(buf, t) do {                                                     \
    const _Float16* bp_ = cb16 + ((((t) << 4) + col) << 8) + (krow << 3);      \
    _Pragma("unroll")                                                          \
    for (int ks_ = 0; ks_ < 8; ++ks_) (buf)[ks_] = *(const half8*)(bp_ + (ks_ << 5)); \
  } while (0)

#define TILE_CORE(buf)                                                         \
  f32x4 ac0 = {0.f, 0.f, 0.f, 0.f}, ac1 = ac0, ac2 = ac0, ac3 = ac0;           \
  _Pragma("unroll")                                                            \
  for (int ks_ = 0; ks_ < 8; ++ks_) {                                          \
    ac0 = __builtin_amdgcn_mfma_f32_16x16x32_f16(a[0][ks_], (buf)[ks_], ac0, 0, 0, 0); \
    ac1 = __builtin_amdgcn_mfma_f32_16x16x32_f16(a[1][ks_], (buf)[ks_], ac1, 0, 0, 0); \
    ac2 = __builtin_amdgcn_mfma_f32_16x16x32_f16(a[2][ks_], (buf)[ks_], ac2, 0, 0, 0); \
    ac3 = __builtin_amdgcn_mfma_f32_16x16x32_f16(a[3][ks_], (buf)[ks_], ac3, 0, 0, 0); \
  }

#define TILE1(buf, t) do {                                                     \
    const float Bk = Bs[((t) << 4) + col];                                     \
    TILE_CORE(buf)                                                             \
    _Pragma("unroll") for (int r_ = 0; r_ < 4; ++r_) {                         \
      mv[0][r_] = fminf(mv[0][r_], __builtin_fmaf(NEG2S, ac0[r_], Bk));        \
      mv[1][r_] = fminf(mv[1][r_], __builtin_fmaf(NEG2S, ac1[r_], Bk));        \
      mv[2][r_] = fminf(mv[2][r_], __builtin_fmaf(NEG2S, ac2[r_], Bk));        \
      mv[3][r_] = fminf(mv[3][r_], __builtin_fmaf(NEG2S, ac3[r_], Bk));        \
    }                                                                          \
  } while (0)

#define P2ONE(accv, m, t)                                                      \
  _Pragma("unroll") for (int r_ = 0; r_ < 4; ++r_) {                           \
    float key_ = __builtin_fmaf(NEG2S, (accv)[r_], Bk);                        \
    if (key_ <= mv[m][r_]) {                                                   \
      int s_ = atomicAdd(&candn, 1);                                           \
      if (s_ < CAPB) { candp[s_] = (m << 4) + (krow << 2) + r_;                \
                       candk[s_] = ((t) << 4) + col; }                         \
    }                                                                          \
  }

#define TILE2(buf, t) do {                                                     \
    const float Bk = Bs[((t) << 4) + col];                                     \
    TILE_CORE(buf)                                                             \
    P2ONE(ac0, 0, t) P2ONE(ac1, 1, t) P2ONE(ac2, 2, t) P2ONE(ac3, 3, t)        \
  } while (0)

// Index kernel: one bh tile per 256-thr block. z tile read from HBM ONCE
// (strided pattern is the measured 1.3 TB/s ceiling -> pay it a single time)
// into a 64 KB LDS fp32 tile; A, a-frags, and exact re-eval all read LDS.
// k-space split over 4 waves (16 B-tiles each, r3-style global dbuf loads);
// exact cross-wave min merge via LDS (min is order-exact). All numeric
// chains bitwise-identical to the verified r3/r6 kernels.
__global__ __launch_bounds__(256) __attribute__((amdgpu_waves_per_eu(2, 2)))
void vq_idx(const float* __restrict__ z, const float* __restrict__ cb,
            const _Float16* __restrict__ cb16, const float* __restrict__ Bsq,
            float* __restrict__ out) {
  __shared__ float zt[256][64];      // [c][w] fp32, 64 KB
  __shared__ float Bs[NEMB];         // 4 KB
  __shared__ float A_lds[64];
  __shared__ float minw[4][64];      // per-wave per-position mins
  __shared__ int   candp[CAPB];
  __shared__ int   candk[CAPB];
  __shared__ float candd[CAPB];
  __shared__ int   candn;

  const int tid = threadIdx.x;
  const int wv = tid >> 6, lane = tid & 63;
  const int bh = blockIdx.x;
  const int zoff = ((bh >> 6) << 20) | ((bh & 63) << 6);  // b*CDIM*4096 + h*64
  const int col = lane & 15, krow = lane >> 4;

  if (tid == 0) candn = 0;
  for (int i = tid; i < NEMB; i += 256) Bs[i] = Bsq[i];

  // ---- stage z tile (the ONLY strided HBM read of z) ----
  {
    const int w4 = (tid & 15) << 2, c0 = tid >> 4;
#pragma unroll
    for (int it = 0; it < 16; ++it) {
      const int c = c0 + (it << 4);
      *(f32x4*)&zt[c][w4] = *(const f32x4*)(z + zoff + ((size_t)c << 12) + w4);
    }
  }
  __syncthreads();

  // ||z||^2 per position (np pairwise order, LDS stride 64), wave 0
  if (tid < 64) A_lds[tid] = np_pairwise_sq256_s(&zt[0][tid], 64);

  // a-frags from LDS: a[m][ks] elem j = fp16(zt[ks*32+krow*8+j][m*16+col])
  half8 a[4][8];
#pragma unroll
  for (int m = 0; m < 4; ++m)
#pragma unroll
    for (int ks = 0; ks < 8; ++ks)
#pragma unroll
      for (int j = 0; j < 8; ++j)
        a[m][ks][j] = (_Float16)zt[ks * 32 + krow * 8 + j][m * 16 + col];

  // ---- pass 1 over this wave's 16 tiles: min key per position ----
  float mv[4][4];
#pragma unroll
  for (int m = 0; m < 4; ++m)
#pragma unroll
    for (int r = 0; r < 4; ++r) mv[m][r] = INFINITY;

  const int tbase = wv << 4;
  half8 b0[8], b1[8];
  LOADB(b0, tbase);
  for (int tt = 0; tt < 16; tt += 2) {
    LOADB(b1, tbase + tt + 1);
    TILE1(b0, tbase + tt);
    if (tt + 2 < 16) LOADB(b0, tbase + tt + 2);
    TILE1(b1, tbase + tt + 1);
  }

  // reduce min across the 16 cols (codes) of each krow group — all lanes active
#pragma unroll
  for (int m = 0; m < 4; ++m)
#pragma unroll
    for (int r = 0; r < 4; ++r) {
      float v = mv[m][r];
      v = fminf(v, __shfl_xor(v, 1));
      v = fminf(v, __shfl_xor(v, 2));
      v = fminf(v, __shfl_xor(v, 4));
      v = fminf(v, __shfl_xor(v, 8));
      mv[m][r] = v;
    }
  if (col == 0) {
#pragma unroll
    for (int m = 0; m < 4; ++m)
#pragma unroll
      for (int r = 0; r < 4; ++r)
        minw[wv][(m << 4) + (krow << 2) + r] = mv[m][r];
  }
  __syncthreads();
  // exact global min over the 4 waves' chunks, + EPS
#pragma unroll
  for (int m = 0; m < 4; ++m)
#pragma unroll
    for (int r = 0; r < 4; ++r) {
      const int pos = (m << 4) + (krow << 2) + r;
      mv[m][r] = fminf(fminf(minw[0][pos], minw[1][pos]),
                       fminf(minw[2][pos], minw[3][pos])) + EPS;
    }

  // ---- pass 2: recompute (bitwise-same) keys, collect candidates ----
  LOADB(b0, tbase);
  for (int tt = 0; tt < 16; tt += 2) {
    LOADB(b1, tbase + tt + 1);
    TILE2(b0, tbase + tt);
    if (tt + 2 < 16) LOADB(b0, tbase + tt + 2);
    TILE2(b1, tbase + tt + 1);
  }
  __syncthreads();

  // ---- exact np-chain re-eval (block-parallel; z from LDS, e via float4) ----
  int n = candn;
  if (n > CAPB) n = CAPB;
  for (int i = tid; i < n; i += 256) {
    const int w = candp[i], k = candk[i];
    const float* ep = cb + ((size_t)k << 8);
    float acc = 0.0f;                     // BLAS chain: sequential ascending c
#pragma unroll 16
    for (int c = 0; c < CDIM; c += 4) {
      const float4 ef = *(const float4*)(ep + c);
      acc = __builtin_fmaf(zt[c + 0][w], ef.x, acc);
      acc = __builtin_fmaf(zt[c + 1][w], ef.y, acc);
      acc = __builtin_fmaf(zt[c + 2][w], ef.z, acc);
      acc = __builtin_fmaf(zt[c + 3][w], ef.w, acc);
    }
    const float tt = A_lds[w] + Bs[k];    // fl(A+B)
    candd[i] = __builtin_fmaf(-2.0f, acc, tt);  // fl(t - 2C), single rounding
  }
  __syncthreads();

  // selection per position: lexicographic (d, k) = np first-index ties
  if (tid < 64) {
    float bd = INFINITY; int bk = 0;
    for (int i = 0; i < n; ++i) {
      if (candp[i] == tid) {
        const float d = candd[i]; const int k = candk[i];
        if (d < bd || (d == bd && k < bk)) { bd = d; bk = k; }
      }
    }
    out[IDX_OFF + (size_t)bh * 64 + tid] = (float)bk;   // fp32 index
  }
}

// z_q + losses in the c-major domain: block = (b, 4 c-rows). Codebook COLUMNS
// (4 KB each) + the b's 4096 indices staged in LDS; z read and z_q written
// fully contiguously (16 KB rows). df = e - z; zq = z + df — identical
// per-element arithmetic to the verified epilogue. Loss in double.
__global__ __launch_bounds__(256) void vq_zq(
    const float* __restrict__ z, const float* __restrict__ cb,
    float* __restrict__ out, double* __restrict__ loss_acc) {
  __shared__ float ecol[4][1024];    // 16 KB
  __shared__ int   idxl[4096];       // 16 KB
  __shared__ double wsum[4];

  const int tid = threadIdx.x;
  const int wv = tid >> 6, lane = tid & 63;
  const int bc = blockIdx.x;               // b*64 + cg
  const int b = bc >> 6, cg = bc & 63;     // c = cg*4 + j
  const size_t base = ((size_t)b << 20) | ((size_t)cg << 14);

  for (int i = tid; i < 4 * 1024; i += 256) {
    const int j = i >> 10, k = i & 1023;
    ecol[j][k] = cb[((size_t)k << 8) + (cg << 2) + j];
  }
  const float* idxf = out + IDX_OFF + ((size_t)b << 12);
  for (int i = tid; i < 4096; i += 256) idxl[i] = (int)idxf[i];
  __syncthreads();

  double lsum = 0.0;
#pragma unroll
  for (int j = 0; j < 4; ++j) {
    const float* zr = z + base + (j << 12);
    float* orow = out + base + (j << 12);
#pragma unroll
    for (int it = 0; it < 4; ++it) {
      const int p4 = ((it << 8) + tid) << 2;
      const f32x4 zv = *(const f32x4*)(zr + p4);
      f32x4 qv;
#pragma unroll
      for (int u = 0; u < 4; ++u) {
        const float e = ecol[j][idxl[p4 + u]];
        const float df = e - zv[u];
        lsum += (double)df * (double)df;
        qv[u] = zv[u] + df;
      }
      *(f32x4*)(orow + p4) = qv;
    }
  }
  for (int off = 32; off; off >>= 1) lsum += __shfl_down(lsum, off);
  if (lane == 0) wsum[wv] = lsum;
  __syncthreads();
  if (tid == 0) {
    double t = wsum[0] + wsum[1] + wsum[2] + wsum[3];
    atomicAdd(loss_acc, t);
  }
}

__global__ void vq_finalize(const double* __restrict__ loss_acc,
                            float* __restrict__ out) {
  double m = *loss_acc / (double)Z_ELEMS;
  out[SC_OFF] = (float)m;
  out[SC_OFF + 1] = (float)(0.25 * m);
}

extern "C" void kernel_launch(void* const* d_in, const int* in_sizes, int n_in,
                              void* d_out, int out_size, void* d_ws,
                              size_t ws_size, hipStream_t stream) {
  (void)n_in; (void)ws_size; (void)out_size;
  const float* z;
  const float* cb;
  if (in_sizes[0] == Z_ELEMS) {
    z = (const float*)d_in[0];
    cb = (const float*)d_in[1];
  } else {
    z = (const float*)d_in[1];
    cb = (const float*)d_in[0];
  }
  float* out = (float*)d_out;
  double* loss = (double*)d_ws;                       // 8 B
  float* Bsq = (float*)((char*)d_ws + 256);           // 4 KB
  _Float16* cb16 = (_Float16*)((char*)d_ws + 8192);   // 512 KB (ws >= 520.2 KB)

  vq_prep<<<dim3(NEMB), dim3(64), 0, stream>>>(cb, Bsq, cb16, loss);
  vq_idx<<<dim3(2048), dim3(256), 0, stream>>>(z, cb, cb16, Bsq, out);
  vq_zq<<<dim3(2048), dim3(256), 0, stream>>>(z, cb, out, loss);
  vq_finalize<<<dim3(1), dim3(1), 0, stream>>>(loss, out);
}